// Round 1
// baseline (641.912 us; speedup 1.0000x reference)
//
#include <hip/hip_runtime.h>
#include <hip/hip_bf16.h>

// Problem constants
#define B_  16
#define S_  2048
#define C_  256
#define QK_ 256
#define H_  8
#define N_  512
#define D_  32
// SCALING = QK^-0.5 = 0.0625, folded into q projection epilogue.

typedef short  bf16x8 __attribute__((ext_vector_type(8)));
typedef float  f32x4  __attribute__((ext_vector_type(4)));
// 4-byte-aligned float4 for es stores (row stride 511 floats => 16B store
// bases are only 4B aligned 3/4 of the time; gfx950 handles unaligned dwordx4).
typedef float  f32x4u __attribute__((ext_vector_type(4), aligned(4)));

__device__ __forceinline__ unsigned short f2bf(float f) {
    union { float f; unsigned u; } v; v.f = f;
    unsigned r = v.u + 0x7fffu + ((v.u >> 16) & 1u);   // RNE
    return (unsigned short)(r >> 16);
}

// Barrier that drains ONLY LDS ops. Unlike __syncthreads(), it does NOT emit
// s_waitcnt vmcnt(0), so global stores stay in flight across it. Correctness:
// every tile/red hazard in k_scores is an LDS-ordering hazard only.
__device__ __forceinline__ void bar_lgkm() {
    asm volatile("s_waitcnt lgkmcnt(0)" ::: "memory");
    __builtin_amdgcn_s_barrier();
}

// ---- K0: prep. blocks [0,256): WqT bf16 transpose; [256,768): k projection.
__global__ void k_prep(const float* __restrict__ Wq,
                       const float* __restrict__ env,
                       const float* __restrict__ Wk,
                       unsigned short* __restrict__ wqt,
                       unsigned short* __restrict__ kbf) {
    __shared__ float erow[256];
    int bid = blockIdx.x, t = threadIdx.x;
    if (bid < 256) {
        // WqT[n][c] = bf16(Wq[c][n])
        wqt[bid * 256 + t] = f2bf(Wq[t * 256 + bid]);
    } else {
        // kbf[h][n][d] = bf16( env[n,:] . Wk[:, h*32+d] )
        int n = bid - 256;
        erow[t] = env[n * 256 + t];
        __syncthreads();
        float acc = 0.f;
#pragma unroll 8
        for (int c = 0; c < 256; ++c) acc += erow[c] * Wk[c * 256 + t];
        int h = t >> 5, d = t & 31;
        kbf[(h * N_ + n) * D_ + d] = f2bf(acc);
    }
}

// ---- K1: q = x @ WqT^T via MFMA (x converted to bf16 inline), scaled -----
// block = 256 thr = 4 waves; block covers 16 rows x 256 cols; wave w: cols w*64..
__global__ __launch_bounds__(256) void k_qproj(
        const float* __restrict__ x,
        const unsigned short* __restrict__ wqt,
        unsigned short* __restrict__ qws) {
    int tid  = threadIdx.x;
    int lane = tid & 63, w = tid >> 6;
    int l15  = lane & 15, quad = lane >> 4;
    int r0   = blockIdx.x * 16;
    int nb   = w * 64;

    const float* arow = x + (size_t)(r0 + l15) * 256 + quad * 8;
    const unsigned short* brow[4];
#pragma unroll
    for (int nt = 0; nt < 4; ++nt)
        brow[nt] = wqt + (size_t)(nb + nt * 16 + l15) * 256 + quad * 8;

    f32x4 acc[4] = {};
#pragma unroll
    for (int kk = 0; kk < 8; ++kk) {
        float4 f0 = *(const float4*)(arow + kk * 32);
        float4 f1 = *(const float4*)(arow + kk * 32 + 4);
        bf16x8 a;
        a[0] = (short)f2bf(f0.x); a[1] = (short)f2bf(f0.y);
        a[2] = (short)f2bf(f0.z); a[3] = (short)f2bf(f0.w);
        a[4] = (short)f2bf(f1.x); a[5] = (short)f2bf(f1.y);
        a[6] = (short)f2bf(f1.z); a[7] = (short)f2bf(f1.w);
#pragma unroll
        for (int nt = 0; nt < 4; ++nt) {
            bf16x8 b = *(const bf16x8*)(brow[nt] + kk * 32);
            acc[nt] = __builtin_amdgcn_mfma_f32_16x16x32_bf16(a, b, acc[nt], 0, 0, 0);
        }
    }
    // C layout: col = lane&15 (qk col), row = quad*4+reg (global row)
#pragma unroll
    for (int nt = 0; nt < 4; ++nt) {
        int col = nb + nt * 16 + l15;
        int h = col >> 5, d = col & 31;
#pragma unroll
        for (int r = 0; r < 4; ++r) {
            int gr = r0 + quad * 4 + r;
            int b = gr >> 11, s = gr & 2047;
            qws[(((size_t)(b * H_ + h)) * S_ + s) * D_ + d] = f2bf(acc[nt][r] * 0.0625f);
        }
    }
}

// ---- K2: scores + softmax + outputs --------------------------------------
// grid 2048: bh = bid>>4 (128), s-block = (bid&15)*128. 4 waves: wave w owns
// n in [w*128, w*128+128). Raw exp values staged (shifted by -1) into padded
// LDS; normalization folded into the writeout, which is 8x ds_read_b128 +
// 8x nontemporal global_store_dwordx4 per thread per s-tile. Barriers are
// lgkmcnt-only so es stores are never drained inside the loop.
#define PADW2 516   // 512+4: quad row stride 4*516 % 32 = 16 -> 2-way max (free)
__global__ __launch_bounds__(256) void k_scores(
        const unsigned short* __restrict__ qws,
        const unsigned short* __restrict__ kbf,
        float* __restrict__ out) {
    float* env_att = out;
    float* causal  = out + (size_t)B_ * H_ * S_;
    float* es      = out + (size_t)2 * B_ * H_ * S_;

    __shared__ float red[4][16];
    __shared__ float p0v[16];
    __shared__ float tile[16 * PADW2];

    int tid  = threadIdx.x;
    int lane = tid & 63, w = tid >> 6;
    int l15  = lane & 15, quad = lane >> 4;

    int bid  = blockIdx.x;
    int bh   = bid >> 4;
    int sblk = (bid & 15) * 128;
    int h    = bh & 7;

    // load 8 B-frags: lane holds kbf[h][n = nb+j*16+l15][quad*8 .. +8)
    const unsigned short* kb = kbf + (size_t)h * N_ * D_;
    int nb = w * 128;
    bf16x8 bf[8];
#pragma unroll
    for (int j = 0; j < 8; ++j)
        bf[j] = *(const bf16x8*)(kb + (size_t)(nb + j * 16 + l15) * D_ + quad * 8);

    const unsigned short* qbase = qws + (size_t)bh * S_ * D_;
    // prefetched A fragment for tile st (issued before the previous tile's
    // store burst so MFMA waits vmcnt(<=stores) not vmcnt(0))
    bf16x8 a = *(const bf16x8*)(qbase + (size_t)(sblk + l15) * D_ + quad * 8);

    for (int st = 0; st < 8; ++st) {
        int s0 = sblk + st * 16;

        f32x4 c[8];
#pragma unroll
        for (int j = 0; j < 8; ++j) {
            f32x4 z = {};
            c[j] = __builtin_amdgcn_mfma_f32_16x16x32_bf16(a, bf[j], z, 0, 0, 0);
        }
        // exp (no max-subtract: |score| < ~3) + per-lane partial row sums
        float psum[4] = {0.f, 0.f, 0.f, 0.f};
#pragma unroll
        for (int j = 0; j < 8; ++j)
#pragma unroll
            for (int r = 0; r < 4; ++r) {
                float e = __expf(c[j][r]);
                c[j][r] = e;
                psum[r] += e;
            }
        // reduce across the 16 lanes of each quad (cols)
#pragma unroll
        for (int off = 1; off < 16; off <<= 1)
#pragma unroll
            for (int r = 0; r < 4; ++r)
                psum[r] += __shfl_xor(psum[r], off, 64);

        bar_lgkm();   // [A] previous writeout's tile READS are done; restage ok

        // stage RAW exp values at col n-1 (n=0 goes to p0v instead)
#pragma unroll
        for (int j = 0; j < 8; ++j) {
            int n = nb + j * 16 + l15;
#pragma unroll
            for (int r = 0; r < 4; ++r)
                if (n != 0) tile[(quad * 4 + r) * PADW2 + (n - 1)] = c[j][r];
        }
        if (l15 == 0) {
#pragma unroll
            for (int r = 0; r < 4; ++r) red[w][quad * 4 + r] = psum[r];
        }
        if (w == 0 && l15 == 0) {
#pragma unroll
            for (int r = 0; r < 4; ++r) p0v[quad * 4 + r] = c[0][r];
        }

        bar_lgkm();   // [B] tile/red/p0v visible

        // prefetch next tile's A before the store burst (keeps its consumer's
        // waitcnt at vmcnt(N), not vmcnt(0))
        if (st < 7)
            a = *(const bf16x8*)(qbase + (size_t)(s0 + 16 + l15) * D_ + quad * 8);

        // writeout: 16 rows x 511 floats, normalize folded in, dwordx4 nt stores
        size_t region = ((size_t)bh * S_ + s0) * 511;
        int t    = tid & 127;
        int rsel = tid >> 7;
#pragma unroll
        for (int rp = 0; rp < 8; ++rp) {
            int row = rp * 2 + rsel;
            float tot = red[0][row] + red[1][row] + red[2][row] + red[3][row];
            float inv = __builtin_amdgcn_rcpf(tot);
            f32x4 v = *(const f32x4*)&tile[row * PADW2 + 4 * t];
            v *= inv;
            float* dst = es + region + (size_t)row * 511 + 4 * t;
            if (t < 127) {
                __builtin_nontemporal_store((f32x4u)v, (f32x4u*)dst);
            } else {           // cols 508..510 (col 511 slot is garbage)
                __builtin_nontemporal_store(v.x, dst);
                __builtin_nontemporal_store(v.y, dst + 1);
                __builtin_nontemporal_store(v.z, dst + 2);
            }
        }
        if (tid < 16) {
            float tot = red[0][tid] + red[1][tid] + red[2][tid] + red[3][tid];
            float p0  = p0v[tid] * __builtin_amdgcn_rcpf(tot);
            int srow  = bh * S_ + s0 + tid;
            causal[srow]  = p0;
            env_att[srow] = 1.0f - p0;
        }
    }
}

extern "C" void kernel_launch(void* const* d_in, const int* in_sizes, int n_in,
                              void* d_out, int out_size, void* d_ws, size_t ws_size,
                              hipStream_t stream) {
    const float* x   = (const float*)d_in[0];
    const float* env = (const float*)d_in[1];
    const float* Wq  = (const float*)d_in[2];
    const float* Wk  = (const float*)d_in[3];
    float* out = (float*)d_out;

    char* ws = (char*)d_ws;
    unsigned short* qws = (unsigned short*)(ws);                 // 16.78 MB
    unsigned short* kbf = (unsigned short*)(ws + 16777216);      // 256 KB
    unsigned short* wqt = (unsigned short*)(ws + 17039360);      // 128 KB

    k_prep  <<<768,  256, 0, stream>>>(Wq, env, Wk, wqt, kbf);
    k_qproj <<<2048, 256, 0, stream>>>(x, wqt, qws);
    k_scores<<<2048, 256, 0, stream>>>(qws, kbf, out);
}